// Round 1
// baseline (4884.655 us; speedup 1.0000x reference)
//
#include <hip/hip_runtime.h>

// GMAN-ish pipeline, fully fused. support = I so every (b,n) token is independent.
// B=64, P=Q=12, N=1024, D=64. Output [B,Q,N] fp32.

#define NB 1024
#define DD 64

__device__ __forceinline__ float fexp(float x) {
    return __builtin_amdgcn_exp2f(x * 1.44269504088896341f);
}
__device__ __forceinline__ float fsigmoid(float x) {
    return __builtin_amdgcn_rcpf(1.0f + fexp(-x));   // exp overflow -> inf -> rcp -> 0 : OK
}
__device__ __forceinline__ float ftanh(float x) {
    return 1.0f - 2.0f * __builtin_amdgcn_rcpf(1.0f + fexp(2.0f * x));  // saturates to +-1 : OK
}

// ---- collapse one DCGRU layer's weights: Wx = W[0:64]+W[128:192], Ws = W[64:128]+W[192:256]
// out layout (floats): Wgx [0,8192) Wgs [8192,16384) Wcx [16384,20480) Wcs [20480,24576)
__global__ void prep_weights(const float* __restrict__ Wg, const float* __restrict__ Wc,
                             float* __restrict__ o) {
    int i = blockIdx.x * 256 + threadIdx.x;
    if (i >= 24576) return;
    if (i < 8192) {
        int k = i >> 7, j = i & 127;
        o[i] = Wg[k * 128 + j] + Wg[(128 + k) * 128 + j];
    } else if (i < 16384) {
        int ii = i - 8192; int k = ii >> 7, j = ii & 127;
        o[i] = Wg[(64 + k) * 128 + j] + Wg[(192 + k) * 128 + j];
    } else if (i < 20480) {
        int ii = i - 16384; int k = ii >> 6, j = ii & 63;
        o[i] = Wc[k * 64 + j] + Wc[(128 + k) * 64 + j];
    } else {
        int ii = i - 20480; int k = ii >> 6, j = ii & 63;
        o[i] = Wc[(64 + k) * 64 + j] + Wc[(192 + k) * 64 + j];
    }
}

// ---- se = relu(SE@W1+b1)@W2+b2, stored TRANSPOSED [d][n] with b_in2 folded in.
__global__ void prep_se(const float* __restrict__ SE, const float* __restrict__ W1,
                        const float* __restrict__ b1, const float* __restrict__ W2,
                        const float* __restrict__ b2, const float* __restrict__ bin2,
                        float* __restrict__ seT) {
    __shared__ float h[64];
    int n = blockIdx.x, d = threadIdx.x;
    float acc = b1[d];
    for (int k = 0; k < 64; k++) acc = fmaf(SE[n * 64 + k], W1[k * 64 + d], acc);
    h[d] = fmaxf(acc, 0.0f);
    __syncthreads();
    float acc2 = b2[d];
    for (int k = 0; k < 64; k++) acc2 = fmaf(h[k], W2[k * 64 + d], acc2);
    seT[d * NB + n] = acc2 + bin2[d];
}

// ---- te[b,p,:] = relu(Wte1[dow]+Wte1[7+tod]+b1)@W2+b2   (one-hot matmul == row gather)
__global__ void prep_te(const int* __restrict__ TE, const float* __restrict__ W1,
                        const float* __restrict__ b1, const float* __restrict__ W2,
                        const float* __restrict__ b2, float* __restrict__ teo) {
    __shared__ float h[64];
    int bp = blockIdx.x;            // b*12 + p
    int b = bp / 12, p = bp - b * 12;
    int d = threadIdx.x;
    int dow = TE[(b * 24 + p) * 2 + 0];
    int tod = TE[(b * 24 + p) * 2 + 1];
    float v = W1[dow * 64 + d] + W1[(7 + tod) * 64 + d] + b1[d];
    h[d] = fmaxf(v, 0.0f);
    __syncthreads();
    float acc = b2[d];
    for (int k = 0; k < 64; k++) acc = fmaf(h[k], W2[k * 64 + d], acc);
    teo[bp * 64 + d] = acc;
}

// ---- fused main: FC_in + STE add + DCGRU L1 + DCGRU L2 (interleaved) + head
__global__ __launch_bounds__(256, 1) void gman_main(
    const float* __restrict__ X, const float* __restrict__ seT, const float* __restrict__ te,
    const float* __restrict__ Win1, const float* __restrict__ bin1, const float* __restrict__ Win2,
    const float* __restrict__ L1w, const float* __restrict__ L2w,
    const float* __restrict__ bg1, const float* __restrict__ bc1,
    const float* __restrict__ bg2, const float* __restrict__ bc2,
    const float* __restrict__ Wo1, const float* __restrict__ bo1,
    const float* __restrict__ Wo2, const float* __restrict__ bo2,
    float* __restrict__ out) {
    const int b = blockIdx.x >> 2;                          // uniform per block
    const int n = ((blockIdx.x & 3) << 8) | threadIdx.x;    // coalesced lanes

    const float* Wgx1 = L1w;          const float* Wgs1 = L1w + 8192;
    const float* Wcx1 = L1w + 16384;  const float* Wcs1 = L1w + 20480;
    const float* Wgx2 = L2w;          const float* Wgs2 = L2w + 8192;
    const float* Wcx2 = L2w + 16384;  const float* Wcs2 = L2w + 20480;

    float s1[64], s2[64];
    #pragma unroll
    for (int d = 0; d < 64; d++) { s1[d] = 0.0f; s2[d] = 0.0f; }

    #pragma unroll 1
    for (int p = 0; p < 12; p++) {
        // ---------- xe = relu(x*Win1+bin1)@Win2 + bin2 + se[n] + te[b,p] ----------
        const float x = X[(b * 12 + p) * NB + n];
        const float* tep = te + (b * 12 + p) * 64;      // uniform -> s_load
        float xe[64];
        #pragma unroll
        for (int d = 0; d < 64; d++) xe[d] = seT[d * NB + n] + tep[d];
        #pragma unroll
        for (int j = 0; j < 64; j++) {
            float h = fmaxf(fmaf(x, Win1[j], bin1[j]), 0.0f);
            #pragma unroll
            for (int d = 0; d < 64; d++) xe[d] = fmaf(h, Win2[j * 64 + d], xe[d]);
        }
        // ---------- layer 1 ----------
        {
            float ga[128];
            #pragma unroll
            for (int j = 0; j < 128; j++) ga[j] = bg1[j];
            #pragma unroll
            for (int k = 0; k < 64; k++) {
                const float xk = xe[k], sk = s1[k];
                #pragma unroll
                for (int j = 0; j < 128; j++)
                    ga[j] = fmaf(xk, Wgx1[k * 128 + j], fmaf(sk, Wgs1[k * 128 + j], ga[j]));
            }
            float c[64];
            #pragma unroll
            for (int j = 0; j < 64; j++) c[j] = bc1[j];
            #pragma unroll
            for (int k = 0; k < 64; k++) {
                const float rk = fsigmoid(ga[k]) * s1[k];   // r computed on the fly
                const float xk = xe[k];
                #pragma unroll
                for (int j = 0; j < 64; j++)
                    c[j] = fmaf(xk, Wcx1[k * 64 + j], fmaf(rk, Wcs1[k * 64 + j], c[j]));
            }
            #pragma unroll
            for (int j = 0; j < 64; j++) {
                float u = fsigmoid(ga[64 + j]);
                s1[j] = u * s1[j] + (1.0f - u) * ftanh(c[j]);
            }
        }
        // ---------- layer 2 (input = new s1) ----------
        {
            float ga[128];
            #pragma unroll
            for (int j = 0; j < 128; j++) ga[j] = bg2[j];
            #pragma unroll
            for (int k = 0; k < 64; k++) {
                const float xk = s1[k], sk = s2[k];
                #pragma unroll
                for (int j = 0; j < 128; j++)
                    ga[j] = fmaf(xk, Wgx2[k * 128 + j], fmaf(sk, Wgs2[k * 128 + j], ga[j]));
            }
            float c[64];
            #pragma unroll
            for (int j = 0; j < 64; j++) c[j] = bc2[j];
            #pragma unroll
            for (int k = 0; k < 64; k++) {
                const float rk = fsigmoid(ga[k]) * s2[k];
                const float xk = s1[k];
                #pragma unroll
                for (int j = 0; j < 64; j++)
                    c[j] = fmaf(xk, Wcx2[k * 64 + j], fmaf(rk, Wcs2[k * 64 + j], c[j]));
            }
            #pragma unroll
            for (int j = 0; j < 64; j++) {
                float u = fsigmoid(ga[64 + j]);
                s2[j] = u * s2[j] + (1.0f - u) * ftanh(c[j]);
            }
        }
    }
    // ---------- head: Y = relu(s2@Wo1+bo1)@Wo2+bo2, write transposed [B,Q,N] ----------
    float y[12];
    #pragma unroll
    for (int q = 0; q < 12; q++) y[q] = bo2[q];
    #pragma unroll
    for (int j = 0; j < 64; j++) {
        float acc = bo1[j];
        #pragma unroll
        for (int k = 0; k < 64; k++) acc = fmaf(s2[k], Wo1[k * 64 + j], acc);
        const float hj = fmaxf(acc, 0.0f);
        #pragma unroll
        for (int q = 0; q < 12; q++) y[q] = fmaf(hj, Wo2[j * 12 + q], y[q]);
    }
    #pragma unroll
    for (int q = 0; q < 12; q++) out[(b * 12 + q) * NB + n] = y[q];
}

extern "C" void kernel_launch(void* const* d_in, const int* in_sizes, int n_in,
                              void* d_out, int out_size, void* d_ws, size_t ws_size,
                              hipStream_t stream) {
    const float* X    = (const float*)d_in[0];
    // d_in[1]=ZC, d_in[2]=ZF unused by the reference
    const float* SE   = (const float*)d_in[3];
    const float* Wse1 = (const float*)d_in[4];
    const float* bse1 = (const float*)d_in[5];
    const float* Wse2 = (const float*)d_in[6];
    const float* bse2 = (const float*)d_in[7];
    const float* Wte1 = (const float*)d_in[8];
    const float* bte1 = (const float*)d_in[9];
    const float* Wte2 = (const float*)d_in[10];
    const float* bte2 = (const float*)d_in[11];
    const float* Win1 = (const float*)d_in[12];
    const float* bin1 = (const float*)d_in[13];
    const float* Win2 = (const float*)d_in[14];
    const float* bin2 = (const float*)d_in[15];
    const float* Wg1  = (const float*)d_in[16];
    const float* bg1  = (const float*)d_in[17];
    const float* Wc1  = (const float*)d_in[18];
    const float* bc1  = (const float*)d_in[19];
    const float* Wg2  = (const float*)d_in[20];
    const float* bg2  = (const float*)d_in[21];
    const float* Wc2  = (const float*)d_in[22];
    const float* bc2  = (const float*)d_in[23];
    const float* Wo1  = (const float*)d_in[24];
    const float* bo1  = (const float*)d_in[25];
    const float* Wo2  = (const float*)d_in[26];
    const float* bo2  = (const float*)d_in[27];
    const int*   TE   = (const int*)d_in[28];

    float* ws  = (float*)d_ws;
    float* L1w = ws;                 //  24576 floats
    float* L2w = ws + 24576;         //  24576 floats
    float* seT = ws + 49152;         //  65536 floats (b_in2 folded in)
    float* teo = ws + 114688;        //  49152 floats  (total 640 KB)
    float* out = (float*)d_out;

    prep_weights<<<96, 256, 0, stream>>>(Wg1, Wc1, L1w);
    prep_weights<<<96, 256, 0, stream>>>(Wg2, Wc2, L2w);
    prep_se<<<1024, 64, 0, stream>>>(SE, Wse1, bse1, Wse2, bse2, bin2, seT);
    prep_te<<<768, 64, 0, stream>>>(TE, Wte1, bte1, Wte2, bte2, teo);
    gman_main<<<256, 256, 0, stream>>>(X, seT, teo, Win1, bin1, Win2, L1w, L2w,
                                       bg1, bc1, bg2, bc2, Wo1, bo1, Wo2, bo2, out);
}